// Round 6
// baseline (250.586 us; speedup 1.0000x reference)
//
#include <hip/hip_runtime.h>
#include <hip/hip_bf16.h>

#define E_MSGS 131072
#define N_NODES 8192
#define D_DIM 256
#define XA_STRIDE 264  // 256 + 8 bf16 pad for ds_read_b128 A-frags

typedef __bf16 bf16x8 __attribute__((ext_vector_type(8)));
typedef float f32x4 __attribute__((ext_vector_type(4)));

// raw workgroup barrier: drains LDS (lgkm) only — vmem prefetch stays in flight
#define BAR() asm volatile("s_waitcnt lgkmcnt(0)\n\ts_barrier" ::: "memory")

// ============ phase 1: padded-bucket scatter + fused sort/perm ============

__global__ void k_scatter(const int* __restrict__ index, int* __restrict__ cursors,
                          int* __restrict__ pad) {
    int e = blockIdx.x * blockDim.x + threadIdx.x;
    int n = index[e];
    int p = atomicAdd(&cursors[n], 1);
    if (p < 64) pad[(n << 6) + p] = e;
}

// blocks 0..2047: one wave per node, rank-sort pad row by (t asc, id asc) in place.
// block 2048: count-desc node permutation.
__global__ void k_sortperm(const float* __restrict__ t, const int* __restrict__ counts,
                           int* __restrict__ pad, int* __restrict__ perm) {
    int tid = threadIdx.x;
    if (blockIdx.x < 2048) {
        int wid = (blockIdx.x * 256 + tid) >> 6;
        int ln = tid & 63;
        int cnt = min(counts[wid], 64);
        int base = wid << 6;
        int e = 0; float tv = 0.f;
        if (ln < cnt) { e = pad[base + ln]; tv = t[e]; }
        int rank = 0;
        for (int j = 0; j < cnt; j++) {
            float tj = __shfl(tv, j);
            int ej = __shfl(e, j);
            rank += (tj < tv) || (tj == tv && ej < e);  // stable: tie -> orig id
        }
        if (ln < cnt) pad[base + rank] = e;
    } else {
        __shared__ int hist[65];
        __shared__ int hcur[65];
        if (tid < 65) hist[tid] = 0;
        __syncthreads();
        int myc[32];
#pragma unroll
        for (int i = 0; i < 32; i++) {
            int c = min(counts[tid * 32 + i], 64);
            myc[i] = c;
            atomicAdd(&hist[c], 1);
        }
        __syncthreads();
        if (tid == 0) {
            int run = 0;
            for (int c = 64; c >= 0; c--) { hcur[c] = run; run += hist[c]; }
        }
        __syncthreads();
#pragma unroll
        for (int i = 0; i < 32; i++) {
            int pos = atomicAdd(&hcur[myc[i]], 1);
            perm[pos] = tid * 32 + i;
        }
    }
}

// ================= phase 2: serial recurrence, DEEP msg prefetch ===============
// r5 structure with ONE change: 3 rotating register prefetch stages keep THREE
// msg rows in flight per wave (r0-r5 all had ~1 — and all collapsed onto the
// same ~1.8 TB/s gather service rate = MLP-starved per Little's law). Stage
// rotation is static via the x3-unrolled loop (no runtime indexing). sid
// addresses run a 2-deep pipeline so the address chain has a full step of slack.

__launch_bounds__(512, 4)
__global__ void k_gru(const float* __restrict__ msg, const float* __restrict__ W,
                      const float* __restrict__ b, const int* __restrict__ counts,
                      const int* __restrict__ spad, const int* __restrict__ perm,
                      float* __restrict__ out) {
    __shared__ __bf16 xA[3][16 * XA_STRIDE];

    int tid  = threadIdx.x;
    int wave = tid >> 6;   // 0..7
    int lane = tid & 63;
    int q    = lane >> 4;
    int l    = lane & 15;
    int node0 = blockIdx.x * 16;

    // ---- W fragments (B operand: B[k][n]=W[n][k]; lane n=32w+16t+l, k=32c+8q+j) ----
    bf16x8 wf[8][2];
#pragma unroll
    for (int t4 = 0; t4 < 2; t4++) {
        const float* wr = W + (32 * wave + 16 * t4 + l) * D_DIM;
#pragma unroll
        for (int c = 0; c < 8; c++) {
            int k0 = 32 * c + 8 * q;
            float4 w0 = *(const float4*)(wr + k0);
            float4 w1 = *(const float4*)(wr + k0 + 4);
            bf16x8 f;
            f[0] = (__bf16)w0.x; f[1] = (__bf16)w0.y; f[2] = (__bf16)w0.z; f[3] = (__bf16)w0.w;
            f[4] = (__bf16)w1.x; f[5] = (__bf16)w1.y; f[6] = (__bf16)w1.z; f[7] = (__bf16)w1.w;
            wf[c][t4] = f;
        }
    }
    float bias[2];
#pragma unroll
    for (int t4 = 0; t4 < 2; t4++) bias[t4] = b[32 * wave + 16 * t4 + l];

    // C-lane node info: quad q owns rows 4q+r -> nodes perm[node0+4q+r]
    int cnt4[4];
#pragma unroll
    for (int r = 0; r < 4; r++) cnt4[r] = min(counts[perm[node0 + 4 * q + r]], 64);
    int S = min(counts[perm[node0]], 64);  // count-desc: first node = block max

    // loader-lane info: lane handles row jrow (0..15), 32B chunk k4 of its cols
    int jrow = lane >> 2;
    int k4 = lane & 3;
    long baseL = (long)perm[node0 + jrow] << 6;  // broadcast x4 lanes
    int colL = 32 * wave + 8 * k4;

    float h[2][4];
#pragma unroll
    for (int t4 = 0; t4 < 2; t4++)
#pragma unroll
        for (int r = 0; r < 4; r++) h[t4][r] = 0.f;

    // ---- prologue: m_0 -> xA[0], m_1 -> xA[1]; stages = m_2,m_3,m_4 in flight;
    //      sid pipeline: sidR0 = pos 5, sidR1 = pos 6 ----
    float4 mS0a, mS0b, mS1a, mS1b, mS2a, mS2b;
    int sidR0, sidR1;
    {
        int sid0 = spad[baseL + 0];
        int sid1 = spad[baseL + 1];
        int sid2 = spad[baseL + 2];
        int sid3 = spad[baseL + 3];
        int sid4 = spad[baseL + 4];
        sidR0 = spad[baseL + 5];
        sidR1 = spad[baseL + 6];
        const float* m0 = msg + (long)sid0 * D_DIM + colL;
        const float* m1 = msg + (long)sid1 * D_DIM + colL;
        const float* m2 = msg + (long)sid2 * D_DIM + colL;
        const float* m3 = msg + (long)sid3 * D_DIM + colL;
        const float* m4 = msg + (long)sid4 * D_DIM + colL;
        float4 a0 = *(const float4*)m0, a1 = *(const float4*)(m0 + 4);
        float4 b0 = *(const float4*)m1, b1 = *(const float4*)(m1 + 4);
        mS0a = *(const float4*)m2; mS0b = *(const float4*)(m2 + 4);
        mS1a = *(const float4*)m3; mS1b = *(const float4*)(m3 + 4);
        mS2a = *(const float4*)m4; mS2b = *(const float4*)(m4 + 4);
        bf16x8 fa, fb;
        fa[0] = (__bf16)a0.x; fa[1] = (__bf16)a0.y; fa[2] = (__bf16)a0.z; fa[3] = (__bf16)a0.w;
        fa[4] = (__bf16)a1.x; fa[5] = (__bf16)a1.y; fa[6] = (__bf16)a1.z; fa[7] = (__bf16)a1.w;
        fb[0] = (__bf16)b0.x; fb[1] = (__bf16)b0.y; fb[2] = (__bf16)b0.z; fb[3] = (__bf16)b0.w;
        fb[4] = (__bf16)b1.x; fb[5] = (__bf16)b1.y; fb[6] = (__bf16)b1.z; fb[7] = (__bf16)b1.w;
        *(bf16x8*)(&xA[0][jrow * XA_STRIDE + colL]) = fa;
        *(bf16x8*)(&xA[1][jrow * XA_STRIDE + colL]) = fb;
    }
    BAR();

    // step s: publish cur (= m_{s+2}) to xA[mb]; issue m_{s+5} into cur (3 in
    // flight); MFMA reads xA[rb] = x_s; epilogue RMWs xA[hb] (m_{s+1} -> x_{s+1}).
    auto step = [&](int s, int rb, int hb, int mb, float4& c0, float4& c1) {
        // (i) publish m_{s+2} (regs -> LDS; buffer mb last read at step s-1)
        {
            bf16x8 f;
            f[0] = (__bf16)c0.x; f[1] = (__bf16)c0.y; f[2] = (__bf16)c0.z; f[3] = (__bf16)c0.w;
            f[4] = (__bf16)c1.x; f[5] = (__bf16)c1.y; f[6] = (__bf16)c1.z; f[7] = (__bf16)c1.w;
            *(bf16x8*)(&xA[mb][jrow * XA_STRIDE + colL]) = f;
        }
        // (ii) issue m_{s+5} into the freed stage; advance 2-deep sid pipeline
        {
            const float* mrow = msg + (long)sidR0 * D_DIM + colL;
            c0 = *(const float4*)mrow;
            c1 = *(const float4*)(mrow + 4);
            sidR0 = sidR1;
            sidR1 = spad[baseL + min(s + 7, 63)];
        }
        // (iii) MFMA: acc = x_s @ W^T
        const __bf16* buf = xA[rb];
        f32x4 acc[2];
#pragma unroll
        for (int t4 = 0; t4 < 2; t4++) acc[t4] = (f32x4){0.f, 0.f, 0.f, 0.f};
#pragma unroll
        for (int c = 0; c < 8; c++) {
            bf16x8 a = *(const bf16x8*)(buf + l * XA_STRIDE + 32 * c + 8 * q);
#pragma unroll
            for (int t4 = 0; t4 < 2; t4++)
                acc[t4] = __builtin_amdgcn_mfma_f32_16x16x32_bf16(a, wf[c][t4], acc[t4], 0, 0, 0);
        }
        // (iv) epilogue: h update (masked) + same-wave LDS RMW x_{s+1} = m + h
#pragma unroll
        for (int t4 = 0; t4 < 2; t4++) {
#pragma unroll
            for (int r = 0; r < 4; r++) {
                float hn = acc[t4][r] + bias[t4];
                bool valid = s < cnt4[r];
                h[t4][r] = valid ? hn : h[t4][r];
                int off = (4 * q + r) * XA_STRIDE + 32 * wave + 16 * t4 + l;
                float mval = (float)xA[hb][off];
                xA[hb][off] = (__bf16)(h[t4][r] + mval);
            }
        }
        BAR();
    };

    int s = 0;
    while (true) {
        if (s >= S) break; step(s, 0, 1, 2, mS0a, mS0b); s++;
        if (s >= S) break; step(s, 1, 2, 0, mS1a, mS1b); s++;
        if (s >= S) break; step(s, 2, 0, 1, mS2a, mS2b); s++;
    }

    // ---- write fp32 h (0 for empty nodes) ----
#pragma unroll
    for (int r = 0; r < 4; r++) {
        int n = perm[node0 + 4 * q + r];
#pragma unroll
        for (int t4 = 0; t4 < 2; t4++)
            out[(long)n * D_DIM + 32 * wave + 16 * t4 + l] = h[t4][r];
    }
}

// ================= launch =================

extern "C" void kernel_launch(void* const* d_in, const int* in_sizes, int n_in,
                              void* d_out, int out_size, void* d_ws, size_t ws_size,
                              hipStream_t stream) {
    const float* msg   = (const float*)d_in[0];
    const int*   index = (const int*)d_in[1];
    const float* t     = (const float*)d_in[2];
    const float* W     = (const float*)d_in[4];
    const float* b     = (const float*)d_in[5];
    float* out = (float*)d_out;

    int* ws = (int*)d_ws;
    int* cursors = ws;                      // [8192] -> ends as counts
    int* pad     = ws + 8192;               // [8192*64]
    int* perm    = ws + 8192 + 8192 * 64;   // [8192]

    // zero cursors + pad in one memset (pad zeros make rows >= cnt safe)
    hipMemsetAsync(cursors, 0, (8192 + 8192 * 64) * sizeof(int), stream);

    k_scatter<<<E_MSGS / 256, 256, 0, stream>>>(index, cursors, pad);
    k_sortperm<<<2049, 256, 0, stream>>>(t, cursors, pad, perm);
    k_gru<<<N_NODES / 16, 512, 0, stream>>>(msg, W, b, cursors, pad, perm, out);
}

// Round 7
// 248.416 us; speedup vs baseline: 1.0087x; 1.0087x over previous
//
#include <hip/hip_runtime.h>
#include <hip/hip_bf16.h>

#define E_MSGS 131072
#define N_NODES 8192
#define D_DIM 256
#define XA_STRIDE 264  // 256 + 8 bf16 pad for ds_read_b128 A-frags

typedef __bf16 bf16x8 __attribute__((ext_vector_type(8)));
typedef float f32x4 __attribute__((ext_vector_type(4)));

// Drain-free workgroup barrier (m201 8-phase idiom): sched_barrier pins LDS ops,
// clobber-free lgkmcnt(0) publishes ds_writes, raw s_barrier syncs. NO "memory"
// clobber -> SIInsertWaitcnts does NOT force vmcnt(0): msg prefetch loads stay
// in flight across the barrier with compiler-counted vmcnt at their true uses.
// (r0-r6's BAR had ::: "memory" -> implicit vmcnt(0) drain every step; that one
// drain explains six rounds of structural changes all landing at ~2.3us/step.)
#define BAR()                                  \
    do {                                       \
        __builtin_amdgcn_sched_barrier(0);     \
        asm volatile("s_waitcnt lgkmcnt(0)");  \
        __builtin_amdgcn_s_barrier();          \
        __builtin_amdgcn_sched_barrier(0);     \
    } while (0)

// ============ phase 1: padded-bucket scatter + fused sort/perm ============

__global__ void k_scatter(const int* __restrict__ index, int* __restrict__ cursors,
                          int* __restrict__ pad) {
    int e = blockIdx.x * blockDim.x + threadIdx.x;
    int n = index[e];
    int p = atomicAdd(&cursors[n], 1);
    if (p < 64) pad[(n << 6) + p] = e;
}

// blocks 0..2047: one wave per node, rank-sort pad row by (t asc, id asc) in place.
// block 2048: count-desc node permutation.
__global__ void k_sortperm(const float* __restrict__ t, const int* __restrict__ counts,
                           int* __restrict__ pad, int* __restrict__ perm) {
    int tid = threadIdx.x;
    if (blockIdx.x < 2048) {
        int wid = (blockIdx.x * 256 + tid) >> 6;
        int ln = tid & 63;
        int cnt = min(counts[wid], 64);
        int base = wid << 6;
        int e = 0; float tv = 0.f;
        if (ln < cnt) { e = pad[base + ln]; tv = t[e]; }
        int rank = 0;
        for (int j = 0; j < cnt; j++) {
            float tj = __shfl(tv, j);
            int ej = __shfl(e, j);
            rank += (tj < tv) || (tj == tv && ej < e);  // stable: tie -> orig id
        }
        if (ln < cnt) pad[base + rank] = e;
    } else {
        __shared__ int hist[65];
        __shared__ int hcur[65];
        if (tid < 65) hist[tid] = 0;
        __syncthreads();
        int myc[32];
#pragma unroll
        for (int i = 0; i < 32; i++) {
            int c = min(counts[tid * 32 + i], 64);
            myc[i] = c;
            atomicAdd(&hist[c], 1);
        }
        __syncthreads();
        if (tid == 0) {
            int run = 0;
            for (int c = 64; c >= 0; c--) { hcur[c] = run; run += hist[c]; }
        }
        __syncthreads();
#pragma unroll
        for (int i = 0; i < 32; i++) {
            int pos = atomicAdd(&hcur[myc[i]], 1);
            perm[pos] = tid * 32 + i;
        }
    }
}

// ================= phase 2: serial recurrence, drain-free barrier ==============
// r6 structure unchanged (8 waves x 32 dims, W in regs, 3-stage register msg
// prefetch, 3-buffer LDS rotation). ONE change: BAR() no longer drains vmcnt,
// so the 3 in-flight msg rows per wave actually pipeline across steps.

__launch_bounds__(512, 4)
__global__ void k_gru(const float* __restrict__ msg, const float* __restrict__ W,
                      const float* __restrict__ b, const int* __restrict__ counts,
                      const int* __restrict__ spad, const int* __restrict__ perm,
                      float* __restrict__ out) {
    __shared__ __bf16 xA[3][16 * XA_STRIDE];

    int tid  = threadIdx.x;
    int wave = tid >> 6;   // 0..7
    int lane = tid & 63;
    int q    = lane >> 4;
    int l    = lane & 15;
    int node0 = blockIdx.x * 16;

    // ---- W fragments (B operand: B[k][n]=W[n][k]; lane n=32w+16t+l, k=32c+8q+j) ----
    bf16x8 wf[8][2];
#pragma unroll
    for (int t4 = 0; t4 < 2; t4++) {
        const float* wr = W + (32 * wave + 16 * t4 + l) * D_DIM;
#pragma unroll
        for (int c = 0; c < 8; c++) {
            int k0 = 32 * c + 8 * q;
            float4 w0 = *(const float4*)(wr + k0);
            float4 w1 = *(const float4*)(wr + k0 + 4);
            bf16x8 f;
            f[0] = (__bf16)w0.x; f[1] = (__bf16)w0.y; f[2] = (__bf16)w0.z; f[3] = (__bf16)w0.w;
            f[4] = (__bf16)w1.x; f[5] = (__bf16)w1.y; f[6] = (__bf16)w1.z; f[7] = (__bf16)w1.w;
            wf[c][t4] = f;
        }
    }
    float bias[2];
#pragma unroll
    for (int t4 = 0; t4 < 2; t4++) bias[t4] = b[32 * wave + 16 * t4 + l];

    // C-lane node info: quad q owns rows 4q+r -> nodes perm[node0+4q+r]
    int cnt4[4];
#pragma unroll
    for (int r = 0; r < 4; r++) cnt4[r] = min(counts[perm[node0 + 4 * q + r]], 64);
    int S = min(counts[perm[node0]], 64);  // count-desc: first node = block max

    // loader-lane info: lane handles row jrow (0..15), 32B chunk k4 of its cols
    int jrow = lane >> 2;
    int k4 = lane & 3;
    long baseL = (long)perm[node0 + jrow] << 6;  // broadcast x4 lanes
    int colL = 32 * wave + 8 * k4;

    float h[2][4];
#pragma unroll
    for (int t4 = 0; t4 < 2; t4++)
#pragma unroll
        for (int r = 0; r < 4; r++) h[t4][r] = 0.f;

    // ---- prologue: m_0 -> xA[0], m_1 -> xA[1]; stages = m_2,m_3,m_4 in flight;
    //      sid pipeline: sidR0 = pos 5, sidR1 = pos 6 ----
    float4 mS0a, mS0b, mS1a, mS1b, mS2a, mS2b;
    int sidR0, sidR1;
    {
        int sid0 = spad[baseL + 0];
        int sid1 = spad[baseL + 1];
        int sid2 = spad[baseL + 2];
        int sid3 = spad[baseL + 3];
        int sid4 = spad[baseL + 4];
        sidR0 = spad[baseL + 5];
        sidR1 = spad[baseL + 6];
        const float* m0 = msg + (long)sid0 * D_DIM + colL;
        const float* m1 = msg + (long)sid1 * D_DIM + colL;
        const float* m2 = msg + (long)sid2 * D_DIM + colL;
        const float* m3 = msg + (long)sid3 * D_DIM + colL;
        const float* m4 = msg + (long)sid4 * D_DIM + colL;
        float4 a0 = *(const float4*)m0, a1 = *(const float4*)(m0 + 4);
        float4 b0 = *(const float4*)m1, b1 = *(const float4*)(m1 + 4);
        mS0a = *(const float4*)m2; mS0b = *(const float4*)(m2 + 4);
        mS1a = *(const float4*)m3; mS1b = *(const float4*)(m3 + 4);
        mS2a = *(const float4*)m4; mS2b = *(const float4*)(m4 + 4);
        bf16x8 fa, fb;
        fa[0] = (__bf16)a0.x; fa[1] = (__bf16)a0.y; fa[2] = (__bf16)a0.z; fa[3] = (__bf16)a0.w;
        fa[4] = (__bf16)a1.x; fa[5] = (__bf16)a1.y; fa[6] = (__bf16)a1.z; fa[7] = (__bf16)a1.w;
        fb[0] = (__bf16)b0.x; fb[1] = (__bf16)b0.y; fb[2] = (__bf16)b0.z; fb[3] = (__bf16)b0.w;
        fb[4] = (__bf16)b1.x; fb[5] = (__bf16)b1.y; fb[6] = (__bf16)b1.z; fb[7] = (__bf16)b1.w;
        *(bf16x8*)(&xA[0][jrow * XA_STRIDE + colL]) = fa;
        *(bf16x8*)(&xA[1][jrow * XA_STRIDE + colL]) = fb;
    }
    BAR();

    // step s: publish cur (= m_{s+2}) to xA[mb]; issue m_{s+5} into cur (3 in
    // flight); MFMA reads xA[rb] = x_s; epilogue RMWs xA[hb] (m_{s+1} -> x_{s+1}).
    auto step = [&](int s, int rb, int hb, int mb, float4& c0, float4& c1) {
        // (i) publish m_{s+2} (regs -> LDS; buffer mb last read at step s-1)
        {
            bf16x8 f;
            f[0] = (__bf16)c0.x; f[1] = (__bf16)c0.y; f[2] = (__bf16)c0.z; f[3] = (__bf16)c0.w;
            f[4] = (__bf16)c1.x; f[5] = (__bf16)c1.y; f[6] = (__bf16)c1.z; f[7] = (__bf16)c1.w;
            *(bf16x8*)(&xA[mb][jrow * XA_STRIDE + colL]) = f;
        }
        // (ii) issue m_{s+5} into the freed stage; advance 2-deep sid pipeline
        {
            const float* mrow = msg + (long)sidR0 * D_DIM + colL;
            c0 = *(const float4*)mrow;
            c1 = *(const float4*)(mrow + 4);
            sidR0 = sidR1;
            sidR1 = spad[baseL + min(s + 7, 63)];
        }
        // (iii) MFMA: acc = x_s @ W^T
        const __bf16* buf = xA[rb];
        f32x4 acc[2];
#pragma unroll
        for (int t4 = 0; t4 < 2; t4++) acc[t4] = (f32x4){0.f, 0.f, 0.f, 0.f};
#pragma unroll
        for (int c = 0; c < 8; c++) {
            bf16x8 a = *(const bf16x8*)(buf + l * XA_STRIDE + 32 * c + 8 * q);
#pragma unroll
            for (int t4 = 0; t4 < 2; t4++)
                acc[t4] = __builtin_amdgcn_mfma_f32_16x16x32_bf16(a, wf[c][t4], acc[t4], 0, 0, 0);
        }
        // (iv) epilogue: h update (masked) + same-wave LDS RMW x_{s+1} = m + h
#pragma unroll
        for (int t4 = 0; t4 < 2; t4++) {
#pragma unroll
            for (int r = 0; r < 4; r++) {
                float hn = acc[t4][r] + bias[t4];
                bool valid = s < cnt4[r];
                h[t4][r] = valid ? hn : h[t4][r];
                int off = (4 * q + r) * XA_STRIDE + 32 * wave + 16 * t4 + l;
                float mval = (float)xA[hb][off];
                xA[hb][off] = (__bf16)(h[t4][r] + mval);
            }
        }
        BAR();
    };

    int s = 0;
    while (true) {
        if (s >= S) break; step(s, 0, 1, 2, mS0a, mS0b); s++;
        if (s >= S) break; step(s, 1, 2, 0, mS1a, mS1b); s++;
        if (s >= S) break; step(s, 2, 0, 1, mS2a, mS2b); s++;
    }

    // ---- write fp32 h (0 for empty nodes) ----
#pragma unroll
    for (int r = 0; r < 4; r++) {
        int n = perm[node0 + 4 * q + r];
#pragma unroll
        for (int t4 = 0; t4 < 2; t4++)
            out[(long)n * D_DIM + 32 * wave + 16 * t4 + l] = h[t4][r];
    }
}

// ================= launch =================

extern "C" void kernel_launch(void* const* d_in, const int* in_sizes, int n_in,
                              void* d_out, int out_size, void* d_ws, size_t ws_size,
                              hipStream_t stream) {
    const float* msg   = (const float*)d_in[0];
    const int*   index = (const int*)d_in[1];
    const float* t     = (const float*)d_in[2];
    const float* W     = (const float*)d_in[4];
    const float* b     = (const float*)d_in[5];
    float* out = (float*)d_out;

    int* ws = (int*)d_ws;
    int* cursors = ws;                      // [8192] -> ends as counts
    int* pad     = ws + 8192;               // [8192*64]
    int* perm    = ws + 8192 + 8192 * 64;   // [8192]

    // zero cursors + pad in one memset (pad zeros make rows >= cnt safe)
    hipMemsetAsync(cursors, 0, (8192 + 8192 * 64) * sizeof(int), stream);

    k_scatter<<<E_MSGS / 256, 256, 0, stream>>>(index, cursors, pad);
    k_sortperm<<<2049, 256, 0, stream>>>(t, cursors, pad, perm);
    k_gru<<<N_NODES / 16, 512, 0, stream>>>(msg, W, b, cursors, pad, perm, out);
}